// Round 4
// baseline (595.713 us; speedup 1.0000x reference)
//
#include <hip/hip_runtime.h>
#include <hip/hip_bf16.h>

#define N_NODES 8192
#define IN_FEAT 256
#define OUT_F   64
#define NHEAD   4
#define HF      256     // NHEAD*OUT_F
#define NEG     0.2f

typedef unsigned short u16;
typedef __attribute__((ext_vector_type(8))) short short8;   // 8 bf16 (4 VGPRs)
typedef __attribute__((ext_vector_type(4))) float f32x4;    // MFMA C/D

__device__ __forceinline__ u16 f2bf(float f) {
    union { unsigned int u; float f; } v; v.f = f;
    unsigned int r = v.u + 0x7FFFu + ((v.u >> 16) & 1u);  // RNE
    return (u16)(r >> 16);
}

// ---------------------------------------------------------------------------
// K0: PWT[k][c] = PW[c][k]  (256x256 fp32 transpose)
// ---------------------------------------------------------------------------
__global__ __launch_bounds__(256) void k_tr(const float* __restrict__ PW,
                                            float* __restrict__ PWT) {
    __shared__ float t[64][65];
    const int bx = (blockIdx.x & 3) * 64;   // k tile
    const int by = (blockIdx.x >> 2) * 64;  // c tile
    const int tx = threadIdx.x & 63;
    const int ty = threadIdx.x >> 6;
    #pragma unroll
    for (int r = ty; r < 64; r += 4)
        t[r][tx] = PW[(size_t)(by + r) * IN_FEAT + bx + tx];
    __syncthreads();
    #pragma unroll
    for (int r = ty; r < 64; r += 4)
        PWT[(size_t)(bx + r) * HF + by + tx] = t[tx][r];
}

// ---------------------------------------------------------------------------
// K1: per RPB rows: support = X@W -> suppT (bf16 [H*64][N]), f1/f2 head dots,
//     proj = X@PWT + proj_b + bias -> d_out (fp32). (Not the bottleneck —
//     invariant ~const across 4 structural variants; left as-is.)
// ---------------------------------------------------------------------------
#define RPB 4
__global__ __launch_bounds__(256, 8) void k_gemm(
    const float* __restrict__ inp,   // [N, 256]
    const float* __restrict__ W,     // [256, 256] (k-major rows)
    const float* __restrict__ U,     // [H*64] flat
    const float* __restrict__ V,     // [H*64] flat
    const float* __restrict__ Bias,  // [256]
    const float* __restrict__ PWT,   // [256 k][256 c]  (transposed proj_w)
    const float* __restrict__ PB,    // [256]
    u16*   __restrict__ suppT,       // [H*64][N] bf16  (feature-major)
    float* __restrict__ f1,          // [H][N]
    float* __restrict__ f2,          // [H][N]
    float* __restrict__ outp)        // [N][256]  proj + bias + proj_b
{
    __shared__ __align__(16) float in_lds[RPB][IN_FEAT];
    const int c  = threadIdx.x;            // output column 0..255
    const int n0 = blockIdx.x * RPB;

    #pragma unroll
    for (int r = 0; r < RPB; ++r)
        in_lds[r][c] = inp[(size_t)(n0 + r) * IN_FEAT + c];
    __syncthreads();

    float accs[RPB], accp[RPB];
    #pragma unroll
    for (int r = 0; r < RPB; ++r) { accs[r] = 0.f; accp[r] = 0.f; }

    const float* wc = W   + c;
    const float* pc = PWT + c;
    float w0 = wc[0 * HF], w1 = wc[1 * HF], w2 = wc[2 * HF], w3 = wc[3 * HF];
    float p0 = pc[0 * HF], p1 = pc[1 * HF], p2 = pc[2 * HF], p3 = pc[3 * HF];

    #pragma unroll 1
    for (int k = 0; k < IN_FEAT; k += 4) {
        const int kn = (k + 4) & 255;          // wrap: last prefetch discarded
        const float nw0 = wc[(kn + 0) * HF];
        const float nw1 = wc[(kn + 1) * HF];
        const float nw2 = wc[(kn + 2) * HF];
        const float nw3 = wc[(kn + 3) * HF];
        const float np0 = pc[(kn + 0) * HF];
        const float np1 = pc[(kn + 1) * HF];
        const float np2 = pc[(kn + 2) * HF];
        const float np3 = pc[(kn + 3) * HF];
        #pragma unroll
        for (int r = 0; r < RPB; ++r) {
            const float4 xv = *(const float4*)&in_lds[r][k];
            accs[r] = fmaf(xv.x, w0, accs[r]);
            accs[r] = fmaf(xv.y, w1, accs[r]);
            accs[r] = fmaf(xv.z, w2, accs[r]);
            accs[r] = fmaf(xv.w, w3, accs[r]);
            accp[r] = fmaf(xv.x, p0, accp[r]);
            accp[r] = fmaf(xv.y, p1, accp[r]);
            accp[r] = fmaf(xv.z, p2, accp[r]);
            accp[r] = fmaf(xv.w, p3, accp[r]);
        }
        w0 = nw0; w1 = nw1; w2 = nw2; w3 = nw3;
        p0 = np0; p1 = np1; p2 = np2; p3 = np3;
    }

    const int h = c >> 6, lane = c & 63;
    const float uv = U[c], vv = V[c];
    const float bb = Bias[c] + PB[c];

    union { short s[4]; unsigned long long q; } sv;
    #pragma unroll
    for (int r = 0; r < RPB; ++r) sv.s[r] = (short)f2bf(accs[r]);
    *(unsigned long long*)(suppT + (size_t)c * N_NODES + n0) = sv.q;

    #pragma unroll
    for (int r = 0; r < RPB; ++r) {
        float s1 = accs[r] * uv, s2 = accs[r] * vv;
        #pragma unroll
        for (int mm = 32; mm > 0; mm >>= 1) {
            s1 += __shfl_xor(s1, mm);
            s2 += __shfl_xor(s2, mm);
        }
        if (lane == 0) {
            f1[h * N_NODES + n0 + r] = s1;
            f2[h * N_NODES + n0 + r] = s2;
        }
        outp[(size_t)(n0 + r) * HF + c] = accp[r] + bb;
    }
}

// ---------------------------------------------------------------------------
// K2: per-head f1 max + factored-exponential tables:
//     EA[h][j] = exp(f1j - f1max)        (branch t>=0 factor, <= 1)
//     EB[h][j] = exp(0.2*(f1j - f1max))  (branch t<0  factor, <= 1)
// ---------------------------------------------------------------------------
__global__ __launch_bounds__(256) void k_prep(const float* __restrict__ f1,
                                              float* __restrict__ f1max,
                                              float* __restrict__ EA,
                                              float* __restrict__ EB) {
    __shared__ float red[256];
    const int h = blockIdx.x;
    float m = -1e30f;
    for (int j = threadIdx.x; j < N_NODES; j += 256)
        m = fmaxf(m, f1[h * N_NODES + j]);
    red[threadIdx.x] = m;
    __syncthreads();
    for (int s = 128; s > 0; s >>= 1) {
        if (threadIdx.x < s) red[threadIdx.x] = fmaxf(red[threadIdx.x], red[threadIdx.x + s]);
        __syncthreads();
    }
    const float fm = red[0];
    if (threadIdx.x == 0) f1max[h] = fm;
    for (int j = threadIdx.x; j < N_NODES; j += 256) {
        const float d = f1[h * N_NODES + j] - fm;
        EA[h * N_NODES + j] = __expf(d);
        EB[h * N_NODES + j] = __expf(NEG * d);
    }
}

// ---------------------------------------------------------------------------
// K3: MFMA attention. Grid = 256 i-tiles x 2 j-halves (512 blocks -> 2
//   blocks/CU -> 32 waves/CU; round-3's grid=256 capped occupancy at 45%).
//   Block: 16 waves = 4 heads x 4 chunks of its 4096-j half; each wave does
//   2 i-subtiles sharing B. Inner loop is exp-free:
//     e = flag * ( EA_j>=TH_i ? EA_j*CA_i : EB_j*CB_i )
//   Blocks emit partial numerators/denominators; k_fin combines.
// ---------------------------------------------------------------------------
#define TI 32
#define JH (N_NODES / 2)            // 4096 per block
#define JSPLIT 4
#define JCHUNK (JH / JSPLIT)        // 1024 per wave

union AttnSMem {
    u16   abits[TI][514];              // 32.9 KB: nibble flags, 4096 local j
    float red[NHEAD][JSPLIT][16][65];  // 66.6 KB: chunk partial numerators
};

__global__ __launch_bounds__(1024, 4) void k_attn_mfma(
    const float* __restrict__ adj,   // [N, N] fp32
    const u16* __restrict__ suppT,   // [H*64][N] bf16 (feature-major)
    const float* __restrict__ EA,    // [H][N] exp(f1 - f1max)
    const float* __restrict__ EB,    // [H][N] exp(0.2*(f1 - f1max))
    const float* __restrict__ f2,    // [H][N]
    const float* __restrict__ f1max, // [H]
    float* __restrict__ pnum,        // [2][N][256] partial numerators
    float* __restrict__ pden)        // [2][H][N]   partial denominators
{
    __shared__ AttnSMem sm;
    __shared__ float den[NHEAD][JSPLIT][TI];

    const int itile = blockIdx.x >> 1;
    const int jh    = blockIdx.x & 1;
    const int i0    = itile * TI;
    const int J0    = jh * JH;
    const int tid   = threadIdx.x;
    const int wv    = tid >> 6;       // 0..15
    const int lane  = tid & 63;
    const int col   = lane & 15;      // m (A) / n (B) / col (C)
    const int quad  = lane >> 4;

    // ---- Phase 1: stage adjacency flags for this j-half (rows 2wv,2wv+1) --
    #pragma unroll
    for (int rr = 0; rr < 2; ++rr) {
        const int r = wv * 2 + rr;
        const float* ar = adj + (size_t)(i0 + r) * N_NODES + J0;
        #pragma unroll 2
        for (int it = 0; it < 8; ++it) {
            const int j = it * 512 + lane * 8;
            const float4 a0 = *(const float4*)(ar + j);
            const float4 a1 = *(const float4*)(ar + j + 4);
            const unsigned v =
                (unsigned)(a0.x != 0.f)        | ((unsigned)(a0.y != 0.f) << 1) |
                ((unsigned)(a0.z != 0.f) << 2) | ((unsigned)(a0.w != 0.f) << 3) |
                ((unsigned)(a1.x != 0.f) << 8) | ((unsigned)(a1.y != 0.f) << 9) |
                ((unsigned)(a1.z != 0.f) << 10)| ((unsigned)(a1.w != 0.f) << 11);
            sm.abits[r][it * 64 + lane] = (u16)v;
        }
    }
    __syncthreads();

    // ---- Phase 2: exp-free flash j-loop, 2 i-subtiles ----
    const int h  = wv & 3;            // head
    const int jc = wv >> 2;           // chunk 0..3 within this j-half
    const float fm   = f1max[h];
    const float f2i0 = f2[(size_t)h * N_NODES + i0 + col];
    const float f2i1 = f2[(size_t)h * N_NODES + i0 + 16 + col];
    const float g0 = fm + f2i0,            g1 = fm + f2i1;
    const float mi0 = fmaxf(g0, NEG * g0), mi1 = fmaxf(g1, NEG * g1); // leaky
    const float CA0 = __expf(g0 - mi0),       CA1 = __expf(g1 - mi1);
    const float CB0 = __expf(NEG * g0 - mi0), CB1 = __expf(NEG * g1 - mi1);
    const float TH0 = __expf(-g0),            TH1 = __expf(-g1);
    const float* EAh = EA + (size_t)h * N_NODES + J0;
    const float* EBh = EB + (size_t)h * N_NODES + J0;
    const u16*   bt  = suppT + (size_t)((h << 6) + col) * N_NODES + J0;

    f32x4 acc0[4], acc1[4];
    #pragma unroll
    for (int t = 0; t < 4; ++t) {
        acc0[t] = (f32x4){0.f, 0.f, 0.f, 0.f};
        acc1[t] = (f32x4){0.f, 0.f, 0.f, 0.f};
    }
    float ls0 = 0.f, ls1 = 0.f;

    const int jb0  = jc * JCHUNK;           // local j within half
    const int jend = jb0 + JCHUNK;
    const int qo   = quad << 3;

    short8 bv[4];
    #pragma unroll
    for (int t = 0; t < 4; ++t)
        bv[t] = *(const short8*)(bt + (size_t)(t << 4) * N_NODES + jb0 + qo);

    #pragma unroll 1
    for (int jb = jb0; jb < jend; jb += 32) {
        const int jq = jb + qo;
        const int jn = ((jb + 32 < jend) ? (jb + 32) : jb0) + qo;
        short8 bn[4];
        #pragma unroll
        for (int t = 0; t < 4; ++t)
            bn[t] = *(const short8*)(bt + (size_t)(t << 4) * N_NODES + jn);

        const float4 ea0 = *(const float4*)(EAh + jq);
        const float4 ea1 = *(const float4*)(EAh + jq + 4);
        const float4 eb0 = *(const float4*)(EBh + jq);
        const float4 eb1 = *(const float4*)(EBh + jq + 4);
        const u16 bw0 = sm.abits[col][(jb >> 3) + quad];        // sub 0 flags
        const u16 bw1 = sm.abits[16 + col][(jb >> 3) + quad];   // sub 1 flags

        const float eav[8] = {ea0.x, ea0.y, ea0.z, ea0.w, ea1.x, ea1.y, ea1.z, ea1.w};
        const float ebv[8] = {eb0.x, eb0.y, eb0.z, eb0.w, eb1.x, eb1.y, eb1.z, eb1.w};
        union { short8 v; unsigned w[4]; } af0, af1;
        float ep0 = 0.f, ep1 = 0.f;
        #pragma unroll
        for (int jj = 0; jj < 8; ++jj) {
            const int sh_jj = (jj & 3) + ((jj >> 2) << 3);
            const bool c0 = (eav[jj] >= TH0);
            const bool c1 = (eav[jj] >= TH1);
            float x0 = (c0 ? eav[jj] : ebv[jj]) * (c0 ? CA0 : CB0);
            float x1 = (c1 ? eav[jj] : ebv[jj]) * (c1 ? CA1 : CB1);
            x0 = ((bw0 >> sh_jj) & 1) ? x0 : 0.f;
            x1 = ((bw1 >> sh_jj) & 1) ? x1 : 0.f;
            ls0 += x0; ls1 += x1;
            if ((jj & 1) == 0) { ep0 = x0; ep1 = x1; }
            else {
                asm("v_cvt_pk_bf16_f32 %0, %1, %2"
                    : "=v"(af0.w[jj >> 1]) : "v"(ep0), "v"(x0));
                asm("v_cvt_pk_bf16_f32 %0, %1, %2"
                    : "=v"(af1.w[jj >> 1]) : "v"(ep1), "v"(x1));
            }
        }

        #pragma unroll
        for (int t = 0; t < 4; ++t)
            acc0[t] = __builtin_amdgcn_mfma_f32_16x16x32_bf16(af0.v, bv[t], acc0[t], 0, 0, 0);
        #pragma unroll
        for (int t = 0; t < 4; ++t)
            acc1[t] = __builtin_amdgcn_mfma_f32_16x16x32_bf16(af1.v, bv[t], acc1[t], 0, 0, 0);

        #pragma unroll
        for (int t = 0; t < 4; ++t) bv[t] = bn[t];
    }

    // chunk-partial denominators: reduce over quads
    ls0 += __shfl_xor(ls0, 16);
    ls0 += __shfl_xor(ls0, 32);
    ls1 += __shfl_xor(ls1, 16);
    ls1 += __shfl_xor(ls1, 32);   // lane L holds chunk lsum for i = L&15

    // ---- Phase 3: combine chunk partials through LDS, emit partials ----
    __syncthreads();                 // all abits reads complete (red overlays)

    if (lane < 16)      den[h][jc][col]      = ls0;
    else if (lane < 32) den[h][jc][16 + col] = ls1;

    const int gid = (jc << 6) | lane;    // 0..255 within head group
    const int row = gid >> 4;            // 0..15
    const int fe  = gid & 15;
    float* pnh = pnum + (size_t)jh * N_NODES * HF;

    // pass 0: subtile 0 (rows i0 .. i0+15)
    #pragma unroll
    for (int reg = 0; reg < 4; ++reg) {
        const int irow = (quad << 2) + reg;                     // C-layout row
        #pragma unroll
        for (int t = 0; t < 4; ++t)
            sm.red[h][jc][irow][(t << 4) | col] = acc0[t][reg];
    }
    __syncthreads();
    {
        float* op = pnh + (size_t)(i0 + row) * HF + (h << 6);
        #pragma unroll
        for (int ff = 0; ff < 4; ++ff) {
            const int feat = (ff << 4) | fe;
            op[feat] = sm.red[h][0][row][feat] + sm.red[h][1][row][feat]
                     + sm.red[h][2][row][feat] + sm.red[h][3][row][feat];
        }
        if (fe == 0)
            pden[((size_t)jh * NHEAD + h) * N_NODES + i0 + row] =
                den[h][0][row] + den[h][1][row] + den[h][2][row] + den[h][3][row];
    }
    __syncthreads();

    // pass 1: subtile 1 (rows i0+16 .. i0+31)
    #pragma unroll
    for (int reg = 0; reg < 4; ++reg) {
        const int irow = (quad << 2) + reg;
        #pragma unroll
        for (int t = 0; t < 4; ++t)
            sm.red[h][jc][irow][(t << 4) | col] = acc1[t][reg];
    }
    __syncthreads();
    {
        float* op = pnh + (size_t)(i0 + 16 + row) * HF + (h << 6);
        #pragma unroll
        for (int ff = 0; ff < 4; ++ff) {
            const int feat = (ff << 4) | fe;
            op[feat] = sm.red[h][0][row][feat] + sm.red[h][1][row][feat]
                     + sm.red[h][2][row][feat] + sm.red[h][3][row][feat];
        }
        if (fe == 0)
            pden[((size_t)jh * NHEAD + h) * N_NODES + i0 + 16 + row] =
                den[h][0][16 + row] + den[h][1][16 + row]
              + den[h][2][16 + row] + den[h][3][16 + row];
    }
}

// ---------------------------------------------------------------------------
// K4: combine the two j-half partials:  out += (n0 + n1) / (d0 + d1)
// ---------------------------------------------------------------------------
__global__ __launch_bounds__(256) void k_fin(const float* __restrict__ pnum,
                                             const float* __restrict__ pden,
                                             float* __restrict__ out) {
    const int c = threadIdx.x;
    const int h = c >> 6;
    #pragma unroll
    for (int rr = 0; rr < 4; ++rr) {
        const int n = blockIdx.x * 4 + rr;
        const float d = pden[(size_t)h * N_NODES + n]
                      + pden[((size_t)NHEAD + h) * N_NODES + n];
        const float s = pnum[(size_t)n * HF + c]
                      + pnum[(size_t)(N_NODES + n) * HF + c];
        out[(size_t)n * HF + c] += s / d;
    }
}

// ---------------------------------------------------------------------------
extern "C" void kernel_launch(void* const* d_in, const int* in_sizes, int n_in,
                              void* d_out, int out_size, void* d_ws, size_t ws_size,
                              hipStream_t stream) {
    const float* inp  = (const float*)d_in[0];  // [8192,256]
    const float* adj  = (const float*)d_in[1];  // [8192,8192]
    const float* W    = (const float*)d_in[2];  // [256,256]
    const float* U    = (const float*)d_in[3];  // [4,64,1]
    const float* V    = (const float*)d_in[4];  // [4,64,1]
    const float* Bias = (const float*)d_in[5];  // [1,256]
    const float* PW   = (const float*)d_in[6];  // [256,256]
    const float* PB   = (const float*)d_in[7];  // [256]
    float* out = (float*)d_out;                 // [8192,256] fp32

    char* ws = (char*)d_ws;
    u16*   suppT = (u16*)(ws);                                   // 4 MiB
    float* f1    = (float*)(ws + (4u << 20));                    // 128 KiB
    float* f2    = (float*)(ws + (4u << 20) + (128u << 10));     // 128 KiB
    float* f1mx  = (float*)(ws + (4u << 20) + (256u << 10));     // 64 B
    float* PWT   = (float*)(ws + (4u << 20) + (320u << 10));     // 256 KiB
    float* EAp   = (float*)(ws + (4u << 20) + (576u << 10));     // 128 KiB
    float* EBp   = (float*)(ws + (4u << 20) + (704u << 10));     // 128 KiB
    float* pden  = (float*)(ws + (4u << 20) + (832u << 10));     // 256 KiB
    float* pnum  = (float*)(ws + (8u << 20));                    // 16 MiB

    k_tr<<<16, 256, 0, stream>>>(PW, PWT);
    k_gemm<<<N_NODES / RPB, 256, 0, stream>>>(inp, W, U, V, Bias, PWT, PB,
                                              suppT, f1, f2, out);
    k_prep<<<NHEAD, 256, 0, stream>>>(f1, f1mx, EAp, EBp);
    k_attn_mfma<<<(N_NODES / TI) * 2, 1024, 0, stream>>>(adj, suppT, EAp, EBp,
                                                         f2, f1mx, pnum, pden);
    k_fin<<<N_NODES / 4, 256, 0, stream>>>(pnum, pden, out);
}

// Round 5
// 588.958 us; speedup vs baseline: 1.0115x; 1.0115x over previous
//
#include <hip/hip_runtime.h>
#include <hip/hip_bf16.h>

#define N_NODES 8192
#define IN_FEAT 256
#define OUT_F   64
#define NHEAD   4
#define HF      256     // NHEAD*OUT_F
#define NEG     0.2f

typedef unsigned short u16;
typedef __attribute__((ext_vector_type(8))) short short8;   // 8 bf16 (4 VGPRs)
typedef __attribute__((ext_vector_type(4))) float f32x4;    // MFMA C/D

__device__ __forceinline__ u16 f2bf(float f) {
    union { unsigned int u; float f; } v; v.f = f;
    unsigned int r = v.u + 0x7FFFu + ((v.u >> 16) & 1u);  // RNE
    return (u16)(r >> 16);
}

// ---------------------------------------------------------------------------
// K0: PWT[k][c] = PW[c][k]  (256x256 fp32 transpose)
// ---------------------------------------------------------------------------
__global__ __launch_bounds__(256) void k_tr(const float* __restrict__ PW,
                                            float* __restrict__ PWT) {
    __shared__ float t[64][65];
    const int bx = (blockIdx.x & 3) * 64;   // k tile
    const int by = (blockIdx.x >> 2) * 64;  // c tile
    const int tx = threadIdx.x & 63;
    const int ty = threadIdx.x >> 6;
    #pragma unroll
    for (int r = ty; r < 64; r += 4)
        t[r][tx] = PW[(size_t)(by + r) * IN_FEAT + bx + tx];
    __syncthreads();
    #pragma unroll
    for (int r = ty; r < 64; r += 4)
        PWT[(size_t)(bx + r) * HF + by + tx] = t[tx][r];
}

// ---------------------------------------------------------------------------
// K1: per RPB rows: support = X@W -> suppT (bf16 [H*64][N]), f1/f2 head dots,
//     proj = X@PWT + proj_b + bias -> d_out (fp32). (Unchanged from round 4.)
// ---------------------------------------------------------------------------
#define RPB 4
__global__ __launch_bounds__(256, 8) void k_gemm(
    const float* __restrict__ inp,   // [N, 256]
    const float* __restrict__ W,     // [256, 256] (k-major rows)
    const float* __restrict__ U,     // [H*64] flat
    const float* __restrict__ V,     // [H*64] flat
    const float* __restrict__ Bias,  // [256]
    const float* __restrict__ PWT,   // [256 k][256 c]  (transposed proj_w)
    const float* __restrict__ PB,    // [256]
    u16*   __restrict__ suppT,       // [H*64][N] bf16  (feature-major)
    float* __restrict__ f1,          // [H][N]
    float* __restrict__ f2,          // [H][N]
    float* __restrict__ outp)        // [N][256]  proj + bias + proj_b
{
    __shared__ __align__(16) float in_lds[RPB][IN_FEAT];
    const int c  = threadIdx.x;            // output column 0..255
    const int n0 = blockIdx.x * RPB;

    #pragma unroll
    for (int r = 0; r < RPB; ++r)
        in_lds[r][c] = inp[(size_t)(n0 + r) * IN_FEAT + c];
    __syncthreads();

    float accs[RPB], accp[RPB];
    #pragma unroll
    for (int r = 0; r < RPB; ++r) { accs[r] = 0.f; accp[r] = 0.f; }

    const float* wc = W   + c;
    const float* pc = PWT + c;
    float w0 = wc[0 * HF], w1 = wc[1 * HF], w2 = wc[2 * HF], w3 = wc[3 * HF];
    float p0 = pc[0 * HF], p1 = pc[1 * HF], p2 = pc[2 * HF], p3 = pc[3 * HF];

    #pragma unroll 1
    for (int k = 0; k < IN_FEAT; k += 4) {
        const int kn = (k + 4) & 255;          // wrap: last prefetch discarded
        const float nw0 = wc[(kn + 0) * HF];
        const float nw1 = wc[(kn + 1) * HF];
        const float nw2 = wc[(kn + 2) * HF];
        const float nw3 = wc[(kn + 3) * HF];
        const float np0 = pc[(kn + 0) * HF];
        const float np1 = pc[(kn + 1) * HF];
        const float np2 = pc[(kn + 2) * HF];
        const float np3 = pc[(kn + 3) * HF];
        #pragma unroll
        for (int r = 0; r < RPB; ++r) {
            const float4 xv = *(const float4*)&in_lds[r][k];
            accs[r] = fmaf(xv.x, w0, accs[r]);
            accs[r] = fmaf(xv.y, w1, accs[r]);
            accs[r] = fmaf(xv.z, w2, accs[r]);
            accs[r] = fmaf(xv.w, w3, accs[r]);
            accp[r] = fmaf(xv.x, p0, accp[r]);
            accp[r] = fmaf(xv.y, p1, accp[r]);
            accp[r] = fmaf(xv.z, p2, accp[r]);
            accp[r] = fmaf(xv.w, p3, accp[r]);
        }
        w0 = nw0; w1 = nw1; w2 = nw2; w3 = nw3;
        p0 = np0; p1 = np1; p2 = np2; p3 = np3;
    }

    const int h = c >> 6, lane = c & 63;
    const float uv = U[c], vv = V[c];
    const float bb = Bias[c] + PB[c];

    union { short s[4]; unsigned long long q; } sv;
    #pragma unroll
    for (int r = 0; r < RPB; ++r) sv.s[r] = (short)f2bf(accs[r]);
    *(unsigned long long*)(suppT + (size_t)c * N_NODES + n0) = sv.q;

    #pragma unroll
    for (int r = 0; r < RPB; ++r) {
        float s1 = accs[r] * uv, s2 = accs[r] * vv;
        #pragma unroll
        for (int mm = 32; mm > 0; mm >>= 1) {
            s1 += __shfl_xor(s1, mm);
            s2 += __shfl_xor(s2, mm);
        }
        if (lane == 0) {
            f1[h * N_NODES + n0 + r] = s1;
            f2[h * N_NODES + n0 + r] = s2;
        }
        outp[(size_t)(n0 + r) * HF + c] = accp[r] + bb;
    }
}

// ---------------------------------------------------------------------------
// K2: per-head f1 max + factored-exponential tables:
//     EA[h][j] = exp(f1j - f1max), EB[h][j] = exp(0.2*(f1j - f1max))
// ---------------------------------------------------------------------------
__global__ __launch_bounds__(256) void k_prep(const float* __restrict__ f1,
                                              float* __restrict__ f1max,
                                              float* __restrict__ EA,
                                              float* __restrict__ EB) {
    __shared__ float red[256];
    const int h = blockIdx.x;
    float m = -1e30f;
    for (int j = threadIdx.x; j < N_NODES; j += 256)
        m = fmaxf(m, f1[h * N_NODES + j]);
    red[threadIdx.x] = m;
    __syncthreads();
    for (int s = 128; s > 0; s >>= 1) {
        if (threadIdx.x < s) red[threadIdx.x] = fmaxf(red[threadIdx.x], red[threadIdx.x + s]);
        __syncthreads();
    }
    const float fm = red[0];
    if (threadIdx.x == 0) f1max[h] = fm;
    for (int j = threadIdx.x; j < N_NODES; j += 256) {
        const float d = f1[h * N_NODES + j] - fm;
        EA[h * N_NODES + j] = __expf(d);
        EB[h * N_NODES + j] = __expf(NEG * d);
    }
}

// ---------------------------------------------------------------------------
// K_bits: pack adjacency (fp32, 256 MiB) into nibble-flag u16 words (16 MiB).
//   Word w of row i covers j = 8w..8w+7: bits 0..3 = j..j+3, bits 8..11 =
//   j+4..j+7 (matches the attn consumer's (jj&3)+((jj>>2)<<3) indexing).
//   One clean HBM-rate stream; removes adj entirely from the attn kernel.
// ---------------------------------------------------------------------------
__global__ __launch_bounds__(256) void k_bits(const float* __restrict__ adj,
                                              u16* __restrict__ gb) {
    const int row = blockIdx.x;
    const int t   = threadIdx.x;
    const float* ar = adj + (size_t)row * N_NODES;
    union { u16 s[4]; unsigned long long q; } w;
    #pragma unroll
    for (int p = 0; p < 4; ++p) {
        const int j = t * 32 + p * 8;
        const float4 a0 = *(const float4*)(ar + j);
        const float4 a1 = *(const float4*)(ar + j + 4);
        w.s[p] = (u16)(
            (unsigned)(a0.x != 0.f)        | ((unsigned)(a0.y != 0.f) << 1) |
            ((unsigned)(a0.z != 0.f) << 2) | ((unsigned)(a0.w != 0.f) << 3) |
            ((unsigned)(a1.x != 0.f) << 8) | ((unsigned)(a1.y != 0.f) << 9) |
            ((unsigned)(a1.z != 0.f) << 10)| ((unsigned)(a1.w != 0.f) << 11));
    }
    *(unsigned long long*)(gb + (size_t)row * 1024 + t * 4) = w.q;
}

// ---------------------------------------------------------------------------
// K3: MFMA attention. Grid 256 (TI=32 rows/block, full j range). 16 waves =
//   4 heads x 4 j-chunks; each wave does 2 i-subtiles sharing B fragments.
//   All iteration loads (B + EA + EB) are distance-1 prefetched into regs ->
//   compute critical path is register-only. e = max(EA_j*CA_i, EB_j*CB_i)
//   (exact: exp monotone; branch t>=0 <=> first product larger). Adjacency
//   comes pre-packed from k_bits: phase 1 stages 64 KB instead of 1 MiB.
// ---------------------------------------------------------------------------
#define TI 32
#define JSPLIT 4
#define JCHUNK (N_NODES / JSPLIT)   // 2048 -> 64 iters/wave
#define ABW 1032                    // u16 stride: 2064 B, 16B-aligned rows

union AttnSMem {
    u16   abits[TI][ABW];              // 66.0 KB: nibble flags, full 8192 j
    float red[NHEAD][JSPLIT][16][65];  // 66.6 KB: chunk partial numerators
};

__global__ __launch_bounds__(1024, 4) void k_attn_mfma(
    const u16* __restrict__ gbits,   // [N][1024] nibble flags
    const u16* __restrict__ suppT,   // [H*64][N] bf16 (feature-major)
    const float* __restrict__ EA,    // [H][N] exp(f1 - f1max)
    const float* __restrict__ EB,    // [H][N] exp(0.2*(f1 - f1max))
    const float* __restrict__ f2,    // [H][N]
    const float* __restrict__ f1max, // [H]
    float* __restrict__ out)         // [N][256] fp32: proj in, proj+attn out
{
    __shared__ AttnSMem sm;
    __shared__ float den[NHEAD][JSPLIT][TI];

    const int i0   = blockIdx.x * TI;
    const int tid  = threadIdx.x;
    const int wv   = tid >> 6;        // 0..15
    const int lane = tid & 63;
    const int col  = lane & 15;       // m (A) / n (B) / col (C)
    const int quad = lane >> 4;

    // ---- Phase 1: stage packed flags (wave wv stages rows 2wv, 2wv+1) ----
    #pragma unroll
    for (int rr = 0; rr < 2; ++rr) {
        const int r = wv * 2 + rr;
        const u16* gr = gbits + (size_t)(i0 + r) * 1024;
        #pragma unroll
        for (int p = 0; p < 2; ++p) {
            const int w0 = p * 512 + lane * 8;
            *(short8*)&sm.abits[r][w0] = *(const short8*)(gr + w0);
        }
    }
    __syncthreads();

    // ---- Phase 2: register-resident flash j-loop, 2 i-subtiles ----
    const int h  = wv & 3;            // head
    const int jc = wv >> 2;           // j-chunk 0..3
    const float fm   = f1max[h];
    const float f2i0 = f2[(size_t)h * N_NODES + i0 + col];
    const float f2i1 = f2[(size_t)h * N_NODES + i0 + 16 + col];
    const float g0 = fm + f2i0,            g1 = fm + f2i1;
    const float mi0 = fmaxf(g0, NEG * g0), mi1 = fmaxf(g1, NEG * g1); // leaky
    const float CA0 = __expf(g0 - mi0),       CA1 = __expf(g1 - mi1);
    const float CB0 = __expf(NEG * g0 - mi0), CB1 = __expf(NEG * g1 - mi1);
    const float* EAh = EA + (size_t)h * N_NODES;
    const float* EBh = EB + (size_t)h * N_NODES;
    const u16*   bt  = suppT + (size_t)((h << 6) + col) * N_NODES;

    f32x4 acc0[4], acc1[4];
    #pragma unroll
    for (int t = 0; t < 4; ++t) {
        acc0[t] = (f32x4){0.f, 0.f, 0.f, 0.f};
        acc1[t] = (f32x4){0.f, 0.f, 0.f, 0.f};
    }
    float ls0 = 0.f, ls1 = 0.f;

    const int jb0  = jc * JCHUNK;
    const int jend = jb0 + JCHUNK;
    const int qo   = quad << 3;

    // preload iteration 0
    short8 bv[4];
    #pragma unroll
    for (int t = 0; t < 4; ++t)
        bv[t] = *(const short8*)(bt + (size_t)(t << 4) * N_NODES + jb0 + qo);
    float4 eaA = *(const float4*)(EAh + jb0 + qo);
    float4 eaB = *(const float4*)(EAh + jb0 + qo + 4);
    float4 ebA = *(const float4*)(EBh + jb0 + qo);
    float4 ebB = *(const float4*)(EBh + jb0 + qo + 4);

    #pragma unroll 1
    for (int jb = jb0; jb < jend; jb += 32) {
        // issue ALL next-iteration loads first (wrap on last: unused)
        const int jn = ((jb + 32 < jend) ? (jb + 32) : jb0) + qo;
        short8 bn[4];
        #pragma unroll
        for (int t = 0; t < 4; ++t)
            bn[t] = *(const short8*)(bt + (size_t)(t << 4) * N_NODES + jn);
        const float4 naA = *(const float4*)(EAh + jn);
        const float4 naB = *(const float4*)(EAh + jn + 4);
        const float4 nbA = *(const float4*)(EBh + jn);
        const float4 nbB = *(const float4*)(EBh + jn + 4);

        const u16 bw0 = sm.abits[col][(jb >> 3) + quad];        // sub 0 flags
        const u16 bw1 = sm.abits[16 + col][(jb >> 3) + quad];   // sub 1 flags

        const float eav[8] = {eaA.x, eaA.y, eaA.z, eaA.w, eaB.x, eaB.y, eaB.z, eaB.w};
        const float ebv[8] = {ebA.x, ebA.y, ebA.z, ebA.w, ebB.x, ebB.y, ebB.z, ebB.w};
        union { short8 v; unsigned w[4]; } af0, af1;
        float ep0 = 0.f, ep1 = 0.f;
        #pragma unroll
        for (int jj = 0; jj < 8; ++jj) {
            const int sh_jj = (jj & 3) + ((jj >> 2) << 3);
            // e = max(EA_j*CA_i, EB_j*CB_i)  (exact leaky-exp factorization)
            float x0 = fmaxf(eav[jj] * CA0, ebv[jj] * CB0);
            float x1 = fmaxf(eav[jj] * CA1, ebv[jj] * CB1);
            x0 = ((bw0 >> sh_jj) & 1) ? x0 : 0.f;
            x1 = ((bw1 >> sh_jj) & 1) ? x1 : 0.f;
            ls0 += x0; ls1 += x1;
            if ((jj & 1) == 0) { ep0 = x0; ep1 = x1; }
            else {
                asm("v_cvt_pk_bf16_f32 %0, %1, %2"
                    : "=v"(af0.w[jj >> 1]) : "v"(ep0), "v"(x0));
                asm("v_cvt_pk_bf16_f32 %0, %1, %2"
                    : "=v"(af1.w[jj >> 1]) : "v"(ep1), "v"(x1));
            }
        }

        #pragma unroll
        for (int t = 0; t < 4; ++t)
            acc0[t] = __builtin_amdgcn_mfma_f32_16x16x32_bf16(af0.v, bv[t], acc0[t], 0, 0, 0);
        #pragma unroll
        for (int t = 0; t < 4; ++t)
            acc1[t] = __builtin_amdgcn_mfma_f32_16x16x32_bf16(af1.v, bv[t], acc1[t], 0, 0, 0);

        // rotate prefetched registers
        #pragma unroll
        for (int t = 0; t < 4; ++t) bv[t] = bn[t];
        eaA = naA; eaB = naB; ebA = nbA; ebB = nbB;
    }

    // chunk-partial denominators: reduce over quads
    ls0 += __shfl_xor(ls0, 16);
    ls0 += __shfl_xor(ls0, 32);
    ls1 += __shfl_xor(ls1, 16);
    ls1 += __shfl_xor(ls1, 32);   // lane L holds chunk lsum for i = L&15

    // ---- Phase 3: combine chunk partials through LDS, 2 subtile passes ----
    __syncthreads();                 // all abits reads complete (red overlays)

    if (lane < 16)      den[h][jc][col]      = ls0;
    else if (lane < 32) den[h][jc][16 + col] = ls1;

    const int gid = (jc << 6) | lane;    // 0..255 within head group
    const int row = gid >> 4;            // 0..15
    const int fe  = gid & 15;

    // pass 0: subtile 0 (rows i0 .. i0+15)
    #pragma unroll
    for (int reg = 0; reg < 4; ++reg) {
        const int irow = (quad << 2) + reg;                     // C-layout row
        #pragma unroll
        for (int t = 0; t < 4; ++t)
            sm.red[h][jc][irow][(t << 4) | col] = acc0[t][reg];
    }
    __syncthreads();
    {
        const float dsum = den[h][0][row] + den[h][1][row]
                         + den[h][2][row] + den[h][3][row];
        const float inv = 1.f / dsum;
        float* op = out + (size_t)(i0 + row) * HF + (h << 6);
        #pragma unroll
        for (int ff = 0; ff < 4; ++ff) {
            const int feat = (ff << 4) | fe;
            const float s = sm.red[h][0][row][feat] + sm.red[h][1][row][feat]
                          + sm.red[h][2][row][feat] + sm.red[h][3][row][feat];
            op[feat] += s * inv;
        }
    }
    __syncthreads();

    // pass 1: subtile 1 (rows i0+16 .. i0+31)
    #pragma unroll
    for (int reg = 0; reg < 4; ++reg) {
        const int irow = (quad << 2) + reg;
        #pragma unroll
        for (int t = 0; t < 4; ++t)
            sm.red[h][jc][irow][(t << 4) | col] = acc1[t][reg];
    }
    __syncthreads();
    {
        const float dsum = den[h][0][16 + row] + den[h][1][16 + row]
                         + den[h][2][16 + row] + den[h][3][16 + row];
        const float inv = 1.f / dsum;
        float* op = out + (size_t)(i0 + 16 + row) * HF + (h << 6);
        #pragma unroll
        for (int ff = 0; ff < 4; ++ff) {
            const int feat = (ff << 4) | fe;
            const float s = sm.red[h][0][row][feat] + sm.red[h][1][row][feat]
                          + sm.red[h][2][row][feat] + sm.red[h][3][row][feat];
            op[feat] += s * inv;
        }
    }
}

// ---------------------------------------------------------------------------
extern "C" void kernel_launch(void* const* d_in, const int* in_sizes, int n_in,
                              void* d_out, int out_size, void* d_ws, size_t ws_size,
                              hipStream_t stream) {
    const float* inp  = (const float*)d_in[0];  // [8192,256]
    const float* adj  = (const float*)d_in[1];  // [8192,8192]
    const float* W    = (const float*)d_in[2];  // [256,256]
    const float* U    = (const float*)d_in[3];  // [4,64,1]
    const float* V    = (const float*)d_in[4];  // [4,64,1]
    const float* Bias = (const float*)d_in[5];  // [1,256]
    const float* PW   = (const float*)d_in[6];  // [256,256]
    const float* PB   = (const float*)d_in[7];  // [256]
    float* out = (float*)d_out;                 // [8192,256] fp32

    char* ws = (char*)d_ws;
    u16*   suppT = (u16*)(ws);                                   // 4 MiB
    float* f1    = (float*)(ws + (4u << 20));                    // 128 KiB
    float* f2    = (float*)(ws + (4u << 20) + (128u << 10));     // 128 KiB
    float* f1mx  = (float*)(ws + (4u << 20) + (256u << 10));     // 64 B
    float* PWT   = (float*)(ws + (4u << 20) + (320u << 10));     // 256 KiB
    float* EAp   = (float*)(ws + (4u << 20) + (576u << 10));     // 128 KiB
    float* EBp   = (float*)(ws + (4u << 20) + (704u << 10));     // 128 KiB
    u16*   gbits = (u16*)(ws + (8u << 20));                      // 16 MiB

    k_bits<<<N_NODES, 256, 0, stream>>>(adj, gbits);
    k_tr<<<16, 256, 0, stream>>>(PW, PWT);
    k_gemm<<<N_NODES / RPB, 256, 0, stream>>>(inp, W, U, V, Bias, PWT, PB,
                                              suppT, f1, f2, out);
    k_prep<<<NHEAD, 256, 0, stream>>>(f1, f1mx, EAp, EBp);
    k_attn_mfma<<<N_NODES / TI, 1024, 0, stream>>>(gbits, suppT, EAp, EBp,
                                                   f2, f1mx, out);
}

// Round 6
// 587.727 us; speedup vs baseline: 1.0136x; 1.0021x over previous
//
#include <hip/hip_runtime.h>
#include <hip/hip_bf16.h>

#define N_NODES 8192
#define IN_FEAT 256
#define OUT_F   64
#define NHEAD   4
#define HF      256     // NHEAD*OUT_F
#define NEG     0.2f

typedef unsigned short u16;
typedef __attribute__((ext_vector_type(8))) short short8;   // 8 bf16 (4 VGPRs)
typedef __attribute__((ext_vector_type(4))) float f32x4;    // MFMA C/D

__device__ __forceinline__ u16 f2bf(float f) {
    union { unsigned int u; float f; } v; v.f = f;
    unsigned int r = v.u + 0x7FFFu + ((v.u >> 16) & 1u);  // RNE
    return (u16)(r >> 16);
}

// ---------------------------------------------------------------------------
// K0: PWT[k][c] = PW[c][k]  (256x256 fp32 transpose)
// ---------------------------------------------------------------------------
__global__ __launch_bounds__(256) void k_tr(const float* __restrict__ PW,
                                            float* __restrict__ PWT) {
    __shared__ float t[64][65];
    const int bx = (blockIdx.x & 3) * 64;   // k tile
    const int by = (blockIdx.x >> 2) * 64;  // c tile
    const int tx = threadIdx.x & 63;
    const int ty = threadIdx.x >> 6;
    #pragma unroll
    for (int r = ty; r < 64; r += 4)
        t[r][tx] = PW[(size_t)(by + r) * IN_FEAT + bx + tx];
    __syncthreads();
    #pragma unroll
    for (int r = ty; r < 64; r += 4)
        PWT[(size_t)(bx + r) * HF + by + tx] = t[tx][r];
}

// ---------------------------------------------------------------------------
// K1: per RPB rows: support = X@W -> suppT (bf16 [H*64][N]), f1/f2 head dots,
//     proj = X@PWT + proj_b + bias -> d_out (fp32). (Unchanged.)
// ---------------------------------------------------------------------------
#define RPB 4
__global__ __launch_bounds__(256, 8) void k_gemm(
    const float* __restrict__ inp,   // [N, 256]
    const float* __restrict__ W,     // [256, 256] (k-major rows)
    const float* __restrict__ U,     // [H*64] flat
    const float* __restrict__ V,     // [H*64] flat
    const float* __restrict__ Bias,  // [256]
    const float* __restrict__ PWT,   // [256 k][256 c]  (transposed proj_w)
    const float* __restrict__ PB,    // [256]
    u16*   __restrict__ suppT,       // [H*64][N] bf16  (feature-major)
    float* __restrict__ f1,          // [H][N]
    float* __restrict__ f2,          // [H][N]
    float* __restrict__ outp)        // [N][256]  proj + bias + proj_b
{
    __shared__ __align__(16) float in_lds[RPB][IN_FEAT];
    const int c  = threadIdx.x;            // output column 0..255
    const int n0 = blockIdx.x * RPB;

    #pragma unroll
    for (int r = 0; r < RPB; ++r)
        in_lds[r][c] = inp[(size_t)(n0 + r) * IN_FEAT + c];
    __syncthreads();

    float accs[RPB], accp[RPB];
    #pragma unroll
    for (int r = 0; r < RPB; ++r) { accs[r] = 0.f; accp[r] = 0.f; }

    const float* wc = W   + c;
    const float* pc = PWT + c;
    float w0 = wc[0 * HF], w1 = wc[1 * HF], w2 = wc[2 * HF], w3 = wc[3 * HF];
    float p0 = pc[0 * HF], p1 = pc[1 * HF], p2 = pc[2 * HF], p3 = pc[3 * HF];

    #pragma unroll 1
    for (int k = 0; k < IN_FEAT; k += 4) {
        const int kn = (k + 4) & 255;          // wrap: last prefetch discarded
        const float nw0 = wc[(kn + 0) * HF];
        const float nw1 = wc[(kn + 1) * HF];
        const float nw2 = wc[(kn + 2) * HF];
        const float nw3 = wc[(kn + 3) * HF];
        const float np0 = pc[(kn + 0) * HF];
        const float np1 = pc[(kn + 1) * HF];
        const float np2 = pc[(kn + 2) * HF];
        const float np3 = pc[(kn + 3) * HF];
        #pragma unroll
        for (int r = 0; r < RPB; ++r) {
            const float4 xv = *(const float4*)&in_lds[r][k];
            accs[r] = fmaf(xv.x, w0, accs[r]);
            accs[r] = fmaf(xv.y, w1, accs[r]);
            accs[r] = fmaf(xv.z, w2, accs[r]);
            accs[r] = fmaf(xv.w, w3, accs[r]);
            accp[r] = fmaf(xv.x, p0, accp[r]);
            accp[r] = fmaf(xv.y, p1, accp[r]);
            accp[r] = fmaf(xv.z, p2, accp[r]);
            accp[r] = fmaf(xv.w, p3, accp[r]);
        }
        w0 = nw0; w1 = nw1; w2 = nw2; w3 = nw3;
        p0 = np0; p1 = np1; p2 = np2; p3 = np3;
    }

    const int h = c >> 6, lane = c & 63;
    const float uv = U[c], vv = V[c];
    const float bb = Bias[c] + PB[c];

    union { short s[4]; unsigned long long q; } sv;
    #pragma unroll
    for (int r = 0; r < RPB; ++r) sv.s[r] = (short)f2bf(accs[r]);
    *(unsigned long long*)(suppT + (size_t)c * N_NODES + n0) = sv.q;

    #pragma unroll
    for (int r = 0; r < RPB; ++r) {
        float s1 = accs[r] * uv, s2 = accs[r] * vv;
        #pragma unroll
        for (int mm = 32; mm > 0; mm >>= 1) {
            s1 += __shfl_xor(s1, mm);
            s2 += __shfl_xor(s2, mm);
        }
        if (lane == 0) {
            f1[h * N_NODES + n0 + r] = s1;
            f2[h * N_NODES + n0 + r] = s2;
        }
        outp[(size_t)(n0 + r) * HF + c] = accp[r] + bb;
    }
}

// ---------------------------------------------------------------------------
// K2: per-head f1 max + factored-exponential tables:
//     EA[h][j] = exp(f1j - f1max), EB[h][j] = exp(0.2*(f1j - f1max))
// ---------------------------------------------------------------------------
__global__ __launch_bounds__(256) void k_prep(const float* __restrict__ f1,
                                              float* __restrict__ f1max,
                                              float* __restrict__ EA,
                                              float* __restrict__ EB) {
    __shared__ float red[256];
    const int h = blockIdx.x;
    float m = -1e30f;
    for (int j = threadIdx.x; j < N_NODES; j += 256)
        m = fmaxf(m, f1[h * N_NODES + j]);
    red[threadIdx.x] = m;
    __syncthreads();
    for (int s = 128; s > 0; s >>= 1) {
        if (threadIdx.x < s) red[threadIdx.x] = fmaxf(red[threadIdx.x], red[threadIdx.x + s]);
        __syncthreads();
    }
    const float fm = red[0];
    if (threadIdx.x == 0) f1max[h] = fm;
    for (int j = threadIdx.x; j < N_NODES; j += 256) {
        const float d = f1[h * N_NODES + j] - fm;
        EA[h * N_NODES + j] = __expf(d);
        EB[h * N_NODES + j] = __expf(NEG * d);
    }
}

// ---------------------------------------------------------------------------
// K_bits: pack adjacency (fp32, 256 MiB) into nibble-flag u16 words (16 MiB).
//   Fully coalesced: one word (8 consecutive j) per thread, flat index.
//   Word w covers j=8w..8w+7: bits 0..3 = j..j+3, bits 8..11 = j+4..j+7.
// ---------------------------------------------------------------------------
__global__ __launch_bounds__(256) void k_bits(const float* __restrict__ adj,
                                              u16* __restrict__ gb) {
    const size_t w = (size_t)blockIdx.x * 256 + threadIdx.x;   // word index
    const float* ap = adj + w * 8;
    const float4 a0 = *(const float4*)ap;
    const float4 a1 = *(const float4*)(ap + 4);
    gb[w] = (u16)(
        (unsigned)(a0.x != 0.f)        | ((unsigned)(a0.y != 0.f) << 1) |
        ((unsigned)(a0.z != 0.f) << 2) | ((unsigned)(a0.w != 0.f) << 3) |
        ((unsigned)(a1.x != 0.f) << 8) | ((unsigned)(a1.y != 0.f) << 9) |
        ((unsigned)(a1.z != 0.f) << 10)| ((unsigned)(a1.w != 0.f) << 11));
}

// ---------------------------------------------------------------------------
// K3: MFMA attention. Grid 256, TI=32, 16 waves = 4 heads x 4 j-chunks,
//   2 i-subtiles per wave sharing B. PING-PONG register pipeline (hand
//   unroll x2, named A/B sets, no rotation movs): consume waits are counted
//   vmcnt on loads issued one full compute-phase earlier — round-5's
//   per-iteration vmcnt(0) drain (forced by the bv[t]=bn[t] rotation at a
//   loop back-edge) is gone. LDS flag words prefetched the same way.
// ---------------------------------------------------------------------------
#define TI 32
#define JSPLIT 4
#define JCHUNK (N_NODES / JSPLIT)   // 2048 -> 32 unrolled-x2 iters/wave
#define ABW 1032                    // u16 stride: 2064 B, 16B-aligned rows

union AttnSMem {
    u16   abits[TI][ABW];              // 66.0 KB: nibble flags, full 8192 j
    float red[NHEAD][JSPLIT][16][65];  // 66.6 KB: chunk partial numerators
};

// load set: 4x short8 B, 4x float4 EA/EB, 2x u16 flags   (JN includes qo)
#define ATTN_LOAD(JN, BV, EAx, EAy, EBx, EBy, BW0, BW1)                      \
  do {                                                                       \
    _Pragma("unroll")                                                        \
    for (int t = 0; t < 4; ++t)                                              \
      BV[t] = *(const short8*)(bt + (size_t)(t << 4) * N_NODES + (JN));      \
    EAx = *(const float4*)(EAh + (JN));                                      \
    EAy = *(const float4*)(EAh + (JN) + 4);                                  \
    EBx = *(const float4*)(EBh + (JN));                                      \
    EBy = *(const float4*)(EBh + (JN) + 4);                                  \
    BW0 = sm.abits[col][(JN) >> 3];                                          \
    BW1 = sm.abits[16 + col][(JN) >> 3];                                     \
  } while (0)

// compute step from one set
#define ATTN_STEP(BV, EAx, EAy, EBx, EBy, BW0, BW1)                          \
  do {                                                                       \
    const float eav[8] = {EAx.x, EAx.y, EAx.z, EAx.w,                        \
                          EAy.x, EAy.y, EAy.z, EAy.w};                       \
    const float ebv[8] = {EBx.x, EBx.y, EBx.z, EBx.w,                        \
                          EBy.x, EBy.y, EBy.z, EBy.w};                       \
    union { short8 v; unsigned w[4]; } af0, af1;                             \
    float ep0 = 0.f, ep1 = 0.f;                                              \
    _Pragma("unroll")                                                        \
    for (int jj = 0; jj < 8; ++jj) {                                         \
      const int sh_jj = (jj & 3) + ((jj >> 2) << 3);                         \
      float x0 = fmaxf(eav[jj] * CA0, ebv[jj] * CB0);                        \
      float x1 = fmaxf(eav[jj] * CA1, ebv[jj] * CB1);                        \
      x0 = (((BW0) >> sh_jj) & 1) ? x0 : 0.f;                                \
      x1 = (((BW1) >> sh_jj) & 1) ? x1 : 0.f;                                \
      ls0 += x0; ls1 += x1;                                                  \
      if ((jj & 1) == 0) { ep0 = x0; ep1 = x1; }                             \
      else {                                                                 \
        asm("v_cvt_pk_bf16_f32 %0, %1, %2"                                   \
            : "=v"(af0.w[jj >> 1]) : "v"(ep0), "v"(x0));                     \
        asm("v_cvt_pk_bf16_f32 %0, %1, %2"                                   \
            : "=v"(af1.w[jj >> 1]) : "v"(ep1), "v"(x1));                     \
      }                                                                      \
    }                                                                        \
    _Pragma("unroll")                                                        \
    for (int t = 0; t < 4; ++t)                                              \
      acc0[t] = __builtin_amdgcn_mfma_f32_16x16x32_bf16(af0.v, BV[t],        \
                                                        acc0[t], 0, 0, 0);   \
    _Pragma("unroll")                                                        \
    for (int t = 0; t < 4; ++t)                                              \
      acc1[t] = __builtin_amdgcn_mfma_f32_16x16x32_bf16(af1.v, BV[t],        \
                                                        acc1[t], 0, 0, 0);   \
  } while (0)

__global__ __launch_bounds__(1024, 4) void k_attn_mfma(
    const u16* __restrict__ gbits,   // [N][1024] nibble flags
    const u16* __restrict__ suppT,   // [H*64][N] bf16 (feature-major)
    const float* __restrict__ EA,    // [H][N] exp(f1 - f1max)
    const float* __restrict__ EB,    // [H][N] exp(0.2*(f1 - f1max))
    const float* __restrict__ f2,    // [H][N]
    const float* __restrict__ f1max, // [H]
    float* __restrict__ out)         // [N][256] fp32: proj in, proj+attn out
{
    __shared__ AttnSMem sm;
    __shared__ float den[NHEAD][JSPLIT][TI];

    const int i0   = blockIdx.x * TI;
    const int tid  = threadIdx.x;
    const int wv   = tid >> 6;        // 0..15
    const int lane = tid & 63;
    const int col  = lane & 15;       // m (A) / n (B) / col (C)
    const int quad = lane >> 4;

    // ---- Phase 1: stage packed flags (wave wv stages rows 2wv, 2wv+1) ----
    #pragma unroll
    for (int rr = 0; rr < 2; ++rr) {
        const int r = wv * 2 + rr;
        const u16* gr = gbits + (size_t)(i0 + r) * 1024;
        #pragma unroll
        for (int p = 0; p < 2; ++p) {
            const int w0 = p * 512 + lane * 8;
            *(short8*)&sm.abits[r][w0] = *(const short8*)(gr + w0);
        }
    }
    __syncthreads();

    // ---- Phase 2: ping-pong flash j-loop, 2 i-subtiles ----
    const int h  = wv & 3;            // head
    const int jc = wv >> 2;           // j-chunk 0..3
    const float fm   = f1max[h];
    const float f2i0 = f2[(size_t)h * N_NODES + i0 + col];
    const float f2i1 = f2[(size_t)h * N_NODES + i0 + 16 + col];
    const float g0 = fm + f2i0,            g1 = fm + f2i1;
    const float mi0 = fmaxf(g0, NEG * g0), mi1 = fmaxf(g1, NEG * g1); // leaky
    const float CA0 = __expf(g0 - mi0),       CA1 = __expf(g1 - mi1);
    const float CB0 = __expf(NEG * g0 - mi0), CB1 = __expf(NEG * g1 - mi1);
    const float* EAh = EA + (size_t)h * N_NODES;
    const float* EBh = EB + (size_t)h * N_NODES;
    const u16*   bt  = suppT + (size_t)((h << 6) + col) * N_NODES;

    f32x4 acc0[4], acc1[4];
    #pragma unroll
    for (int t = 0; t < 4; ++t) {
        acc0[t] = (f32x4){0.f, 0.f, 0.f, 0.f};
        acc1[t] = (f32x4){0.f, 0.f, 0.f, 0.f};
    }
    float ls0 = 0.f, ls1 = 0.f;

    const int jb0  = jc * JCHUNK;
    const int jend = jb0 + JCHUNK;
    const int qo   = quad << 3;

    short8 bvA[4], bvB[4];
    float4 eaA0, eaA1, ebA0, ebA1;
    float4 eaB0, eaB1, ebB0, ebB1;
    u16 bwA0, bwA1, bwB0, bwB1;

    ATTN_LOAD(jb0 + qo, bvA, eaA0, eaA1, ebA0, ebA1, bwA0, bwA1);

    #pragma unroll 1
    for (int jb = jb0; jb < jend; jb += 64) {
        const int j1 = jb + 32 + qo;                       // JCHUNK % 64 == 0
        ATTN_LOAD(j1, bvB, eaB0, eaB1, ebB0, ebB1, bwB0, bwB1);
        ATTN_STEP(bvA, eaA0, eaA1, ebA0, ebA1, bwA0, bwA1);
        const int j2 = ((jb + 64 < jend) ? (jb + 64) : jb0) + qo;  // wrap: unused
        ATTN_LOAD(j2, bvA, eaA0, eaA1, ebA0, ebA1, bwA0, bwA1);
        ATTN_STEP(bvB, eaB0, eaB1, ebB0, ebB1, bwB0, bwB1);
    }

    // chunk-partial denominators: reduce over quads
    ls0 += __shfl_xor(ls0, 16);
    ls0 += __shfl_xor(ls0, 32);
    ls1 += __shfl_xor(ls1, 16);
    ls1 += __shfl_xor(ls1, 32);   // lane L holds chunk lsum for i = L&15

    // ---- Phase 3: combine chunk partials through LDS, 2 subtile passes ----
    __syncthreads();                 // all abits reads complete (red overlays)

    if (lane < 16)      den[h][jc][col]      = ls0;
    else if (lane < 32) den[h][jc][16 + col] = ls1;

    const int gid = (jc << 6) | lane;    // 0..255 within head group
    const int row = gid >> 4;            // 0..15
    const int fe  = gid & 15;

    // pass 0: subtile 0 (rows i0 .. i0+15)
    #pragma unroll
    for (int reg = 0; reg < 4; ++reg) {
        const int irow = (quad << 2) + reg;                     // C-layout row
        #pragma unroll
        for (int t = 0; t < 4; ++t)
            sm.red[h][jc][irow][(t << 4) | col] = acc0[t][reg];
    }
    __syncthreads();
    {
        const float dsum = den[h][0][row] + den[h][1][row]
                         + den[h][2][row] + den[h][3][row];
        const float inv = 1.f / dsum;
        float* op = out + (size_t)(i0 + row) * HF + (h << 6);
        #pragma unroll
        for (int ff = 0; ff < 4; ++ff) {
            const int feat = (ff << 4) | fe;
            const float s = sm.red[h][0][row][feat] + sm.red[h][1][row][feat]
                          + sm.red[h][2][row][feat] + sm.red[h][3][row][feat];
            op[feat] += s * inv;
        }
    }
    __syncthreads();

    // pass 1: subtile 1 (rows i0+16 .. i0+31)
    #pragma unroll
    for (int reg = 0; reg < 4; ++reg) {
        const int irow = (quad << 2) + reg;
        #pragma unroll
        for (int t = 0; t < 4; ++t)
            sm.red[h][jc][irow][(t << 4) | col] = acc1[t][reg];
    }
    __syncthreads();
    {
        const float dsum = den[h][0][16 + row] + den[h][1][16 + row]
                         + den[h][2][16 + row] + den[h][3][16 + row];
        const float inv = 1.f / dsum;
        float* op = out + (size_t)(i0 + 16 + row) * HF + (h << 6);
        #pragma unroll
        for (int ff = 0; ff < 4; ++ff) {
            const int feat = (ff << 4) | fe;
            const float s = sm.red[h][0][row][feat] + sm.red[h][1][row][feat]
                          + sm.red[h][2][row][feat] + sm.red[h][3][row][feat];
            op[feat] += s * inv;
        }
    }
}

// ---------------------------------------------------------------------------
extern "C" void kernel_launch(void* const* d_in, const int* in_sizes, int n_in,
                              void* d_out, int out_size, void* d_ws, size_t ws_size,
                              hipStream_t stream) {
    const float* inp  = (const float*)d_in[0];  // [8192,256]
    const float* adj  = (const float*)d_in[1];  // [8192,8192]
    const float* W    = (const float*)d_in[2];  // [256,256]
    const float* U    = (const float*)d_in[3];  // [4,64,1]
    const float* V    = (const float*)d_in[4];  // [4,64,1]
    const float* Bias = (const float*)d_in[5];  // [1,256]
    const float* PW   = (const float*)d_in[6];  // [256,256]
    const float* PB   = (const float*)d_in[7];  // [256]
    float* out = (float*)d_out;                 // [8192,256] fp32

    char* ws = (char*)d_ws;
    u16*   suppT = (u16*)(ws);                                   // 4 MiB
    float* f1    = (float*)(ws + (4u << 20));                    // 128 KiB
    float* f2    = (float*)(ws + (4u << 20) + (128u << 10));     // 128 KiB
    float* f1mx  = (float*)(ws + (4u << 20) + (256u << 10));     // 64 B
    float* PWT   = (float*)(ws + (4u << 20) + (320u << 10));     // 256 KiB
    float* EAp   = (float*)(ws + (4u << 20) + (576u << 10));     // 128 KiB
    float* EBp   = (float*)(ws + (4u << 20) + (704u << 10));     // 128 KiB
    u16*   gbits = (u16*)(ws + (8u << 20));                      // 16 MiB

    k_bits<<<(N_NODES * 1024) / 256, 256, 0, stream>>>(adj, gbits);
    k_tr<<<16, 256, 0, stream>>>(PW, PWT);
    k_gemm<<<N_NODES / RPB, 256, 0, stream>>>(inp, W, U, V, Bias, PWT, PB,
                                              suppT, f1, f2, out);
    k_prep<<<NHEAD, 256, 0, stream>>>(f1, f1mx, EAp, EBp);
    k_attn_mfma<<<N_NODES / TI, 1024, 0, stream>>>(gbits, suppT, EAp, EBp,
                                                   f2, f1mx, out);
}